// Round 3
// baseline (719.929 us; speedup 1.0000x reference)
//
#include <hip/hip_runtime.h>
#include <math.h>

#define NNODES 100000
#define BSHIFT 7
#define BSIZE 128

// ---------- bucketed CSR build ----------

__global__ __launch_bounds__(256) void k_bhist(const int* __restrict__ dst, int* __restrict__ bcnt,
                                               int E, int nbuck) {
    __shared__ int h[800];
    for (int k = threadIdx.x; k < nbuck; k += 256) h[k] = 0;
    __syncthreads();
    int nv = E >> 2;
    for (int i = blockIdx.x * 256 + threadIdx.x; i < nv; i += gridDim.x * 256) {
        int4 d = ((const int4*)dst)[i];
        atomicAdd(&h[d.x >> BSHIFT], 1);
        atomicAdd(&h[d.y >> BSHIFT], 1);
        atomicAdd(&h[d.z >> BSHIFT], 1);
        atomicAdd(&h[d.w >> BSHIFT], 1);
    }
    if (blockIdx.x == 0) {
        for (int k = (nv << 2) + threadIdx.x; k < E; k += 256)
            atomicAdd(&h[dst[k] >> BSHIFT], 1);
    }
    __syncthreads();
    for (int k = threadIdx.x; k < nbuck; k += 256)
        if (h[k]) atomicAdd(&bcnt[k], h[k]);
}

__global__ __launch_bounds__(1024) void k_bscan(const int* __restrict__ bcnt, int* __restrict__ bptr,
                                                int* __restrict__ bcur, int* __restrict__ rowptr,
                                                int nbuck, int N, int E) {
    __shared__ int s[1024];
    int t = threadIdx.x;
    int v = (t < nbuck) ? bcnt[t] : 0;
    s[t] = v;
    __syncthreads();
    #pragma unroll
    for (int off = 1; off < 1024; off <<= 1) {
        int u = (t >= off) ? s[t - off] : 0;
        __syncthreads();
        s[t] += u;
        __syncthreads();
    }
    if (t < nbuck) {
        int ex = s[t] - v;
        bptr[t] = ex;
        bcur[t] = ex;
    }
    if (t == 0) {
        bptr[nbuck] = E;
        rowptr[N] = E;
    }
}

__global__ __launch_bounds__(256) void k_bscatter(const int* __restrict__ src, const int* __restrict__ dst,
                                                  int* __restrict__ bcur, int2* __restrict__ staging, int E) {
    int i = blockIdx.x * 256 + threadIdx.x;
    int i4 = i * 4;
    if (i4 + 3 < E) {
        int4 s = *(const int4*)(src + i4);
        int4 d = *(const int4*)(dst + i4);
        int p0 = atomicAdd(&bcur[d.x >> BSHIFT], 1);
        int p1 = atomicAdd(&bcur[d.y >> BSHIFT], 1);
        int p2 = atomicAdd(&bcur[d.z >> BSHIFT], 1);
        int p3 = atomicAdd(&bcur[d.w >> BSHIFT], 1);
        staging[p0] = make_int2(s.x, d.x);
        staging[p1] = make_int2(s.y, d.y);
        staging[p2] = make_int2(s.z, d.z);
        staging[p3] = make_int2(s.w, d.w);
    } else {
        for (int k = i4; k < E; k++) {
            int pos = atomicAdd(&bcur[dst[k] >> BSHIFT], 1);
            staging[pos] = make_int2(src[k], dst[k]);
        }
    }
}

// one block per bucket: LDS per-node count + scan -> rowptr/dinv, then local scatter of src
__global__ __launch_bounds__(256) void k_bucket_csr(const int2* __restrict__ staging, const int* __restrict__ bptr,
                                                    int* __restrict__ rowptr, int* __restrict__ ssort,
                                                    float* __restrict__ dinv, int N) {
    __shared__ int lcnt[BSIZE], lpre[BSIZE];
    int b = blockIdx.x, t = threadIdx.x;
    int node0 = b << BSHIFT;
    int bbase = bptr[b], bend = bptr[b + 1];
    if (t < BSIZE) lcnt[t] = 0;
    __syncthreads();
    for (int e = bbase + t; e < bend; e += 256)
        atomicAdd(&lcnt[staging[e].y - node0], 1);
    __syncthreads();
    if (t < BSIZE) lpre[t] = lcnt[t];
    __syncthreads();
    #pragma unroll
    for (int off = 1; off < BSIZE; off <<= 1) {
        int u = 0;
        if (t < BSIZE && t >= off) u = lpre[t - off];
        __syncthreads();
        if (t < BSIZE) lpre[t] += u;
        __syncthreads();
    }
    if (t < BSIZE) {
        int node = node0 + t;
        if (node < N) {
            rowptr[node] = bbase + lpre[t] - lcnt[t];
            dinv[node] = rsqrtf((float)(lcnt[t] + 1));  // +1 self-loop
        }
        lpre[t] -= lcnt[t];  // reuse as local cursor (exclusive prefix)
    }
    __syncthreads();
    for (int e = bbase + t; e < bend; e += 256) {
        int2 p = staging[e];
        int pos = atomicAdd(&lpre[p.y - node0], 1);
        ssort[bbase + pos] = p.x;  // writes confined to this bucket's segment (L2-hot)
    }
}

// ---------- G = dinv[i] * (X @ W) ----------
__global__ __launch_bounds__(256) void k_transform(const float* __restrict__ X, const float* __restrict__ W,
                                                   const float* __restrict__ dinv, float* __restrict__ G, int N) {
    int lane = threadIdx.x & 63;
    int wid = threadIdx.x >> 6;
    float w[64];
    #pragma unroll
    for (int k = 0; k < 64; k++) w[k] = W[k * 64 + lane];
    int wave = blockIdx.x * 4 + wid;
    int nw = gridDim.x * 4;
    for (int i = wave; i < N; i += nw) {
        const float4* xr = (const float4*)(X + (size_t)i * 64);
        float a0 = 0.f, a1 = 0.f, a2 = 0.f, a3 = 0.f;
        #pragma unroll
        for (int kk = 0; kk < 16; kk++) {
            float4 x4 = xr[kk];
            a0 = fmaf(x4.x, w[4 * kk + 0], a0);
            a1 = fmaf(x4.y, w[4 * kk + 1], a1);
            a2 = fmaf(x4.z, w[4 * kk + 2], a2);
            a3 = fmaf(x4.w, w[4 * kk + 3], a3);
        }
        G[(size_t)i * 64 + lane] = ((a0 + a1) + (a2 + a3)) * dinv[i];
    }
}

// ---------- out = relu(dinv[i] * (G[i] + sum_j G[j]) + b) ----------
__global__ __launch_bounds__(256) void k_agg(const float* __restrict__ G, const int* __restrict__ rowptr,
                                             const int* __restrict__ ssort, const float* __restrict__ dinv,
                                             const float* __restrict__ bias, float* __restrict__ O, int N) {
    int lane = threadIdx.x & 63;
    int wid = threadIdx.x >> 6;
    int sub = lane >> 4;
    int l = lane & 15;
    int i = blockIdx.x * 4 + wid;
    if (i >= N) return;
    int beg = rowptr[i], end = rowptr[i + 1];
    float ax = 0.f, ay = 0.f, az = 0.f, aw = 0.f;
    int e = beg + sub;
    for (; e + 4 < end; e += 8) {
        int sA = ssort[e];
        int sB = ssort[e + 4];
        float4 gA = *(const float4*)(G + (size_t)sA * 64 + 4 * l);
        float4 gB = *(const float4*)(G + (size_t)sB * 64 + 4 * l);
        ax += gA.x + gB.x;
        ay += gA.y + gB.y;
        az += gA.z + gB.z;
        aw += gA.w + gB.w;
    }
    if (e < end) {
        int sA = ssort[e];
        float4 gA = *(const float4*)(G + (size_t)sA * 64 + 4 * l);
        ax += gA.x; ay += gA.y; az += gA.z; aw += gA.w;
    }
    #pragma unroll
    for (int mask = 16; mask <= 32; mask <<= 1) {
        ax += __shfl_xor(ax, mask);
        ay += __shfl_xor(ay, mask);
        az += __shfl_xor(az, mask);
        aw += __shfl_xor(aw, mask);
    }
    float4 gs = *(const float4*)(G + (size_t)i * 64 + 4 * l);
    float4 b4 = *(const float4*)(bias + 4 * l);
    float di = dinv[i];
    if (sub == 0) {
        float4 r;
        r.x = fmaxf(fmaf(di, ax + gs.x, b4.x), 0.f);
        r.y = fmaxf(fmaf(di, ay + gs.y, b4.y), 0.f);
        r.z = fmaxf(fmaf(di, az + gs.z, b4.z), 0.f);
        r.w = fmaxf(fmaf(di, aw + gs.w, b4.w), 0.f);
        *(float4*)(O + (size_t)i * 64 + 4 * l) = r;
    }
}

// ---------- softmax(H @ Wfc + bfc) ----------
__global__ __launch_bounds__(256) void k_fc_softmax(const float* __restrict__ H, const float* __restrict__ Wfc,
                                                    const float* __restrict__ bfc, float* __restrict__ O, int N) {
    __shared__ float wf[64 * 16];
    __shared__ float bf[16];
    int t = threadIdx.x;
    for (int k = t; k < 1024; k += 256) wf[k] = Wfc[k];
    if (t < 16) bf[t] = bfc[t];
    __syncthreads();
    int gid = blockIdx.x * 256 + t;
    int node = gid >> 4;
    int c = gid & 15;
    if (node >= N) return;
    const float4* hv = (const float4*)(H + (size_t)node * 64);
    float acc = bf[c];
    #pragma unroll
    for (int kk = 0; kk < 16; kk++) {
        float4 h4 = hv[kk];
        acc = fmaf(h4.x, wf[(4 * kk + 0) * 16 + c], acc);
        acc = fmaf(h4.y, wf[(4 * kk + 1) * 16 + c], acc);
        acc = fmaf(h4.z, wf[(4 * kk + 2) * 16 + c], acc);
        acc = fmaf(h4.w, wf[(4 * kk + 3) * 16 + c], acc);
    }
    float m = acc;
    #pragma unroll
    for (int mask = 1; mask < 16; mask <<= 1) m = fmaxf(m, __shfl_xor(m, mask));
    float ex = expf(acc - m);
    float s = ex;
    #pragma unroll
    for (int mask = 1; mask < 16; mask <<= 1) s += __shfl_xor(s, mask);
    O[(size_t)node * 16 + c] = ex / s;
}

extern "C" void kernel_launch(void* const* d_in, const int* in_sizes, int n_in,
                              void* d_out, int out_size, void* d_ws, size_t ws_size,
                              hipStream_t stream) {
    const float* x   = (const float*)d_in[0];
    const int*   ei  = (const int*)d_in[1];
    const float* W1  = (const float*)d_in[2];
    const float* b1  = (const float*)d_in[3];
    const float* W2  = (const float*)d_in[4];
    const float* b2  = (const float*)d_in[5];
    const float* Wfc = (const float*)d_in[6];
    const float* bfc = (const float*)d_in[7];
    float* out = (float*)d_out;
    const int N = NNODES;
    const int E = in_sizes[1] / 2;
    const int nbuck = (N + BSIZE - 1) >> BSHIFT;  // 782

    char* ws = (char*)d_ws;
    size_t off = 0;
    auto take = [&](size_t bytes) {
        char* p = ws + off;
        off = (off + bytes + 255) & ~(size_t)255;
        return p;
    };
    float* bufA   = (float*)take((size_t)N * 64 * 4);   // staging aliases bufA (consumed before transform writes it)
    float* bufB   = (float*)take((size_t)N * 64 * 4);
    int*   ssort  = (int*)take((size_t)E * 4);
    int*   rowptr = (int*)take((size_t)(N + 1) * 4);
    float* dinv   = (float*)take((size_t)N * 4);
    int*   bcnt   = (int*)take((size_t)(nbuck + 1) * 4);
    int*   bptr   = (int*)take((size_t)(nbuck + 1) * 4);
    int*   bcur   = (int*)take((size_t)nbuck * 4);
    int2*  staging = (int2*)bufA;

    const int* e_src = ei;
    const int* e_dst = ei + E;

    hipMemsetAsync(bcnt, 0, (size_t)nbuck * 4, stream);
    int ET = (E + 3) / 4;
    k_bhist<<<256, 256, 0, stream>>>(e_dst, bcnt, E, nbuck);
    k_bscan<<<1, 1024, 0, stream>>>(bcnt, bptr, bcur, rowptr, nbuck, N, E);
    k_bscatter<<<(ET + 255) / 256, 256, 0, stream>>>(e_src, e_dst, bcur, staging, E);
    k_bucket_csr<<<nbuck, 256, 0, stream>>>(staging, bptr, rowptr, ssort, dinv, N);

    k_transform<<<2048, 256, 0, stream>>>(x, W1, dinv, bufA, N);
    k_agg<<<(N + 3) / 4, 256, 0, stream>>>(bufA, rowptr, ssort, dinv, b1, bufB, N);
    k_transform<<<2048, 256, 0, stream>>>(bufB, W2, dinv, bufA, N);
    k_agg<<<(N + 3) / 4, 256, 0, stream>>>(bufA, rowptr, ssort, dinv, b2, bufB, N);
    k_fc_softmax<<<(N * 16 + 255) / 256, 256, 0, stream>>>(bufB, Wfc, bfc, out, N);
}